// Round 3
// baseline (399.911 us; speedup 1.0000x reference)
//
#include <hip/hip_runtime.h>

// SlayerNet SNN forward, MI355X.
// pot1 = FIR129(w1@x) [fused] ; s1 = spike-scan(pot1) [bit-packed] ;
// pot2 = w2@FIR129(s1) ; s2 = spike-scan(pot2) -> d_out (fp32).
// Spike scans: speculative block-parallel + exact sequential fixup
// (state = last 15 spike bits; mask match => bitwise-exact state).

#define T_LEN   65536
#define NCH     250
#define NO1     25
#define KTAPS   129      // taps d=0..128, eps[d] = srm[128-d]
#define PAD     128
#define SRM_LEN 257
#define REF_LEN 16
#define THETA_F 10.0f
#define LBLK    128      // scan block length (== 4 x 32-bit words)
#define NBK     512      // NBK*LBLK == T_LEN
#define WARM    128      // speculative warm-up steps
#define TS      256      // conv tile size
#define NWORDS  (T_LEN / 32)

// One gen_spikes step. Matches JAX: u = p + buf[0]; s = (u>=theta);
// buf = shift(buf) + s*ref_next  (mul then add, fp32, no contraction).
__device__ __forceinline__ void srm_step(float p, const float (&rn)[15], float (&b)[15],
                                         unsigned &m, float &sf_out) {
  float u = p + b[0];
  unsigned sp = (u >= THETA_F) ? 1u : 0u;
  float sf = sp ? 1.0f : 0.0f;
#pragma unroll
  for (int j = 0; j < 14; ++j) b[j] = __fadd_rn(b[j + 1], __fmul_rn(sf, rn[j]));
  b[14] = __fmul_rn(sf, rn[14]);
  m = (m << 1) | sp;
  sf_out = sf;
}

__global__ void k_fill(float* out, float v) {
  out[blockIdx.x * 256 + threadIdx.x] = v;
}

// K1 (fused): pot1[o][t] = sum_d eps[d] * (w1 @ x)[o][t-d]
__global__ __launch_bounds__(TS) void k_pot1(const float* __restrict__ x,
                                             const float* __restrict__ w1,
                                             const float* __restrict__ srm,
                                             float* __restrict__ pot1) {
  __shared__ float ys[NO1][TS + PAD];  // 25 x 384
  __shared__ float eps[KTAPS];
  const int tid = threadIdx.x;
  const int t0 = blockIdx.x * TS;
  const int g0 = t0 - PAD;
  float acc0[NO1], acc1[NO1];
#pragma unroll
  for (int o = 0; o < NO1; ++o) { acc0[o] = 0.0f; acc1[o] = 0.0f; }
  const int gA = g0 + tid;
  const int gB = g0 + TS + tid;
  const bool vB = tid < PAD;
  for (int c = 0; c < NCH; ++c) {
    const float* xr = x + (size_t)c * T_LEN;
    float xa = (gA >= 0) ? xr[gA] : 0.0f;
    float xb = (vB && gB >= 0) ? xr[gB] : 0.0f;
#pragma unroll
    for (int o = 0; o < NO1; ++o) {
      float w = w1[o * NCH + c];
      acc0[o] = __builtin_fmaf(w, xa, acc0[o]);
      acc1[o] = __builtin_fmaf(w, xb, acc1[o]);
    }
  }
#pragma unroll
  for (int o = 0; o < NO1; ++o) {
    ys[o][tid] = acc0[o];
    if (vB) ys[o][TS + tid] = acc1[o];
  }
  for (int j = tid; j < KTAPS; j += TS) eps[j] = srm[PAD - j];
  __syncthreads();
  for (int o = 0; o < NO1; ++o) {
    float a = 0.0f;
#pragma unroll 3
    for (int d = 0; d < KTAPS; ++d) a = __builtin_fmaf(eps[d], ys[o][PAD + tid - d], a);
    pot1[(size_t)o * T_LEN + t0 + tid] = a;
  }
}

// K4: pot2[t] = sum_o w2[o] * FIR129(s1[o])[t], s1 bit-packed.
__global__ __launch_bounds__(TS) void k_pot2(const unsigned* __restrict__ s1p,
                                             const float* __restrict__ srm,
                                             const float* __restrict__ w2,
                                             float* __restrict__ pot2) {
  __shared__ float xs[NO1][TS + PAD];
  __shared__ float eps[KTAPS];
  __shared__ float w2s[NO1];
  const int tid = threadIdx.x;
  const int t0 = blockIdx.x * TS;
  const int g0 = t0 - PAD;
  for (int o = 0; o < NO1; ++o) {
    const unsigned* pr = s1p + o * NWORDS;
    for (int j = tid; j < TS + PAD; j += TS) {
      int g = g0 + j;
      float v = 0.0f;
      if (g >= 0) v = (float)((pr[g >> 5] >> (g & 31)) & 1u);
      xs[o][j] = v;
    }
  }
  for (int j = tid; j < KTAPS; j += TS) eps[j] = srm[PAD - j];
  if (tid < NO1) w2s[tid] = w2[tid];
  __syncthreads();
  float accf = 0.0f;
  for (int o = 0; o < NO1; ++o) {
    float a = 0.0f;
#pragma unroll 3
    for (int d = 0; d < KTAPS; ++d) a = __builtin_fmaf(eps[d], xs[o][PAD + tid - d], a);
    accf = __builtin_fmaf(w2s[o], a, accf);
  }
  pot2[t0 + tid] = accf;
}

// Speculative scan: one thread per (channel, block). WARM steps from assumed
// zero state, then LBLK emitted steps; records entry mask + exit mask/state.
template <int C, bool PACKED>
__global__ __launch_bounds__(256) void k_scan_spec(const float* __restrict__ pot,
                                                   const float* __restrict__ refk,
                                                   float* __restrict__ s,
                                                   unsigned* __restrict__ sp_,
                                                   unsigned* __restrict__ specin_m,
                                                   unsigned* __restrict__ specout_m,
                                                   float* __restrict__ specout_b) {
  int idx = blockIdx.x * 256 + threadIdx.x;
  if (idx >= C * NBK) return;
  int c = idx / NBK;
  int bb = idx - c * NBK;
  int tsr = bb * LBLK - WARM;
  float rn[15];
#pragma unroll
  for (int j = 0; j < 15; ++j) rn[j] = refk[j + 1];
  float b[15];
#pragma unroll
  for (int j = 0; j < 15; ++j) b[j] = 0.0f;
  unsigned m = 0;
  const float* prow = pot + (size_t)c * T_LEN;
  float* srow = PACKED ? nullptr : (s + (size_t)c * T_LEN);
  unsigned* srowp = PACKED ? (sp_ + (size_t)c * NWORDS) : nullptr;
  for (int k = 0; k < WARM + LBLK; k += 4) {
    if (k == WARM) specin_m[idx] = m & 0x7FFFu;
    int t = tsr + k;
    if (t < 0) continue;
    float4 pv = *(const float4*)(prow + t);
    float s0, s1v, s2, s3;
    srm_step(pv.x, rn, b, m, s0);
    srm_step(pv.y, rn, b, m, s1v);
    srm_step(pv.z, rn, b, m, s2);
    srm_step(pv.w, rn, b, m, s3);
    if (k >= WARM) {
      if (PACKED) {
        if (((t + 3) & 31) == 31) srowp[(t - 28) >> 5] = __brev(m);
      } else {
        *(float4*)(srow + t) = make_float4(s0, s1v, s2, s3);
      }
    }
  }
  specout_m[idx] = m & 0x7FFFu;
#pragma unroll
  for (int j = 0; j < 15; ++j) specout_b[idx * 16 + j] = b[j];
}

// Exact fixup: lane c walks its blocks carrying the true state; on mask match
// adopt speculative exit (bit-exact), else recompute the 128 steps.
template <int C, bool PACKED>
__global__ __launch_bounds__(64) void k_scan_fix(const float* __restrict__ pot,
                                                 const float* __restrict__ refk,
                                                 float* __restrict__ s,
                                                 unsigned* __restrict__ sp_,
                                                 const unsigned* __restrict__ specin_m,
                                                 const unsigned* __restrict__ specout_m,
                                                 const float* __restrict__ specout_b) {
  int c = threadIdx.x;
  if (c >= C) return;
  float rn[15];
#pragma unroll
  for (int j = 0; j < 15; ++j) rn[j] = refk[j + 1];
  float b[15];
#pragma unroll
  for (int j = 0; j < 15; ++j) b[j] = 0.0f;
  unsigned m = 0;
  bool haveB = true;
  const float* prow = pot + (size_t)c * T_LEN;
  float* srow = PACKED ? nullptr : (s + (size_t)c * T_LEN);
  unsigned* srowp = PACKED ? (sp_ + (size_t)c * NWORDS) : nullptr;

  for (int g = 0; g < NBK / 8; ++g) {
    int base = c * NBK + g * 8;
    uint4 ia = *(const uint4*)(specin_m + base);
    uint4 ib = *(const uint4*)(specin_m + base + 4);
    uint4 oa = *(const uint4*)(specout_m + base);
    uint4 ob = *(const uint4*)(specout_m + base + 4);
    unsigned iv[8] = {ia.x, ia.y, ia.z, ia.w, ib.x, ib.y, ib.z, ib.w};
    unsigned ov[8] = {oa.x, oa.y, oa.z, oa.w, ob.x, ob.y, ob.z, ob.w};
#pragma unroll
    for (int r = 0; r < 8; ++r) {
      int bb = g * 8 + r;
      if ((m & 0x7FFFu) == iv[r]) {
        m = ov[r];
        haveB = false;
      } else {
        if (!haveB) {  // bb>=1 here: block 0 entry mask is always 0 == initial m
          int pb = (c * NBK + bb - 1) * 16;
#pragma unroll
          for (int q = 0; q < 15; ++q) b[q] = specout_b[pb + q];
          haveB = true;
        }
        int t0 = bb * LBLK;
        for (int t = t0; t < t0 + LBLK; t += 4) {
          float4 pv = *(const float4*)(prow + t);
          float s0, s1v, s2, s3;
          srm_step(pv.x, rn, b, m, s0);
          srm_step(pv.y, rn, b, m, s1v);
          srm_step(pv.z, rn, b, m, s2);
          srm_step(pv.w, rn, b, m, s3);
          if (PACKED) {
            if (((t + 3) & 31) == 31) srowp[(t - 28) >> 5] = __brev(m);
          } else {
            *(float4*)(srow + t) = make_float4(s0, s1v, s2, s3);
          }
        }
        haveB = true;
      }
    }
  }
}

extern "C" void kernel_launch(void* const* d_in, const int* in_sizes, int n_in,
                              void* d_out, int out_size, void* d_ws, size_t ws_size,
                              hipStream_t stream) {
  const float* x    = (const float*)d_in[0];  // 250*65536
  const float* srm  = (const float*)d_in[1];  // 257
  const float* refk = (const float*)d_in[2];  // 16
  const float* w1   = (const float*)d_in[3];  // 25*250
  const float* w2   = (const float*)d_in[4];  // 25
  float* out = (float*)d_out;

  // input sanity -> distinct sentinels
  float bad = 0.0f;
  if (n_in != 5) bad = 3.0f;
  else if (in_sizes[0] != NCH * T_LEN) bad = 4.0f;
  else if (in_sizes[1] != SRM_LEN)     bad = 5.0f;
  else if (in_sizes[2] != REF_LEN)     bad = 6.0f;
  else if (in_sizes[3] != NO1 * NCH)   bad = 7.0f;
  else if (in_sizes[4] != NO1)         bad = 8.0f;
  else if (out_size != T_LEN)          bad = 9.0f;
  if (bad != 0.0f) {
    k_fill<<<T_LEN / 256, 256, 0, stream>>>(out, bad);
    return;
  }

  size_t off = 0;
  auto alloc = [&](size_t bytes) { size_t o = off; off = (off + bytes + 255) & ~(size_t)255; return o; };
  char* ws = (char*)d_ws;
  size_t oP1  = alloc((size_t)NO1 * T_LEN * 4);        // 6.55 MB
  size_t oS1P = alloc((size_t)NO1 * NWORDS * 4);       // 205 KB
  size_t oP2  = alloc((size_t)T_LEN * 4);              // 262 KB
  size_t oSI1 = alloc((size_t)NO1 * NBK * 4);
  size_t oSO1 = alloc((size_t)NO1 * NBK * 4);
  size_t oSB1 = alloc((size_t)NO1 * NBK * 16 * 4);     // 819 KB
  size_t oSI2 = alloc((size_t)NBK * 4);
  size_t oSO2 = alloc((size_t)NBK * 4);
  size_t oSB2 = alloc((size_t)NBK * 16 * 4);
  if (ws_size < off) {  // sentinel 2.0: workspace too small
    k_fill<<<T_LEN / 256, 256, 0, stream>>>(out, 2.0f);
    return;
  }

  float*    pot1 = (float*)(ws + oP1);
  unsigned* s1p  = (unsigned*)(ws + oS1P);
  float*    pot2 = (float*)(ws + oP2);
  unsigned* si1  = (unsigned*)(ws + oSI1);
  unsigned* so1  = (unsigned*)(ws + oSO1);
  float*    sb1  = (float*)(ws + oSB1);
  unsigned* si2  = (unsigned*)(ws + oSI2);
  unsigned* so2  = (unsigned*)(ws + oSO2);
  float*    sb2  = (float*)(ws + oSB2);

  k_pot1<<<T_LEN / TS, TS, 0, stream>>>(x, w1, srm, pot1);
  k_scan_spec<NO1, true><<<(NO1 * NBK + 255) / 256, 256, 0, stream>>>(
      pot1, refk, nullptr, s1p, si1, so1, sb1);
  k_scan_fix<NO1, true><<<1, 64, 0, stream>>>(pot1, refk, nullptr, s1p, si1, so1, sb1);
  k_pot2<<<T_LEN / TS, TS, 0, stream>>>(s1p, srm, w2, pot2);
  k_scan_spec<1, false><<<(NBK + 255) / 256, 256, 0, stream>>>(
      pot2, refk, out, nullptr, si2, so2, sb2);
  k_scan_fix<1, false><<<1, 64, 0, stream>>>(pot2, refk, out, nullptr, si2, so2, sb2);
}

// Round 4
// 182.105 us; speedup vs baseline: 2.1960x; 2.1960x over previous
//
#include <hip/hip_runtime.h>

// SlayerNet SNN forward, MI355X.
// pot1 = FIR129(w1@x) [fused, ILP-unrolled] ; s1 = spike-scan(pot1) [bit-packed] ;
// pot2 = FIR129(w2@s1) [linearity swap] ; s2 = spike-scan(pot2) -> d_out (fp32).
// Spike scans: speculative block-parallel + exact fixup (state = last 15 spike
// bits; 15-bit mask match => bitwise-exact state, so spec results are adopted
// verbatim; fixup uses wave-ballot chain checks, 64 blocks per iteration).

#define T_LEN   65536
#define NCH     250
#define NO1     25
#define KTAPS   129      // taps d=0..128, eps[d] = srm[128-d]
#define PAD     128
#define SRM_LEN 257
#define REF_LEN 16
#define THETA_F 10.0f
#define LBLK    128      // scan block length (== 4 x 32-bit words)
#define NBK     512      // NBK*LBLK == T_LEN
#define WARM    128      // speculative warm-up steps
#define TS      256      // conv tile size
#define NWORDS  (T_LEN / 32)
#define CU_UNR  10       // channel unroll (250 = 25 * 10)

// One gen_spikes step. Matches JAX: u = p + buf[0]; s = (u>=theta);
// buf = shift(buf) + s*ref_next  (mul then add, fp32, no contraction).
__device__ __forceinline__ void srm_step(float p, const float (&rn)[15], float (&b)[15],
                                         unsigned &m, float &sf_out) {
  float u = p + b[0];
  unsigned sp = (u >= THETA_F) ? 1u : 0u;
  float sf = sp ? 1.0f : 0.0f;
#pragma unroll
  for (int j = 0; j < 14; ++j) b[j] = __fadd_rn(b[j + 1], __fmul_rn(sf, rn[j]));
  b[14] = __fmul_rn(sf, rn[14]);
  m = (m << 1) | sp;
  sf_out = sf;
}

__global__ void k_fill(float* out, float v) {
  out[blockIdx.x * 256 + threadIdx.x] = v;
}

// Matmul accumulation for one tile window, unrolled x10 for ILP.
template <bool GUARD>
__device__ __forceinline__ void pot1_accum(const float* __restrict__ x,
                                           const float* __restrict__ w1,
                                           int gA, int gB, bool vB,
                                           float (&acc0)[NO1], float (&acc1)[NO1]) {
  for (int cb = 0; cb < NCH; cb += CU_UNR) {
    float xa[CU_UNR], xb[CU_UNR];
#pragma unroll
    for (int u = 0; u < CU_UNR; ++u) {
      const float* xr = x + (size_t)(cb + u) * T_LEN;
      xa[u] = (!GUARD || gA >= 0) ? xr[gA] : 0.0f;
      xb[u] = (vB && (!GUARD || gB >= 0)) ? xr[gB] : 0.0f;
    }
#pragma unroll
    for (int u = 0; u < CU_UNR; ++u) {
#pragma unroll
      for (int o = 0; o < NO1; ++o) {
        float w = w1[o * NCH + cb + u];  // uniform -> scalar load
        acc0[o] = __builtin_fmaf(w, xa[u], acc0[o]);
        acc1[o] = __builtin_fmaf(w, xb[u], acc1[o]);
      }
    }
  }
}

// K1 (fused): pot1[o][t] = sum_d eps[d] * (w1 @ x)[o][t-d]
__global__ __launch_bounds__(TS) void k_pot1(const float* __restrict__ x,
                                             const float* __restrict__ w1,
                                             const float* __restrict__ srm,
                                             float* __restrict__ pot1) {
  __shared__ __align__(16) float ys[NO1][TS + PAD];  // 25 x 384
  const int tid = threadIdx.x;
  const int t0 = blockIdx.x * TS;
  const int g0 = t0 - PAD;
  const int gA = g0 + tid;
  const int gB = g0 + TS + tid;
  const bool vB = tid < PAD;
  float acc0[NO1], acc1[NO1];
#pragma unroll
  for (int o = 0; o < NO1; ++o) { acc0[o] = 0.0f; acc1[o] = 0.0f; }
  if (g0 >= 0) pot1_accum<false>(x, w1, gA, gB, vB, acc0, acc1);
  else         pot1_accum<true >(x, w1, gA, gB, vB, acc0, acc1);
#pragma unroll
  for (int o = 0; o < NO1; ++o) {
    ys[o][tid] = acc0[o];
    if (vB) ys[o][TS + tid] = acc1[o];
  }
  __syncthreads();
  // FIR: 4 consecutive outputs per thread, float4 LDS window, scalar-pipe taps
  const int q = tid & 63;
  const int op = tid >> 6;   // 0..3
  const int tloc = q * 4;
  for (int pass = 0; pass < 7; ++pass) {
    int o = pass * 4 + op;
    if (o < NO1) {
      float wf[TS / 64 * 0 + 132];
#pragma unroll
      for (int i = 0; i < 33; ++i) {
        float4 v = *(const float4*)&ys[o][tloc + 4 * i];
        wf[4 * i] = v.x; wf[4 * i + 1] = v.y; wf[4 * i + 2] = v.z; wf[4 * i + 3] = v.w;
      }
      float o0 = 0.0f, o1 = 0.0f, o2 = 0.0f, o3 = 0.0f;
#pragma unroll
      for (int d = 0; d < KTAPS; ++d) {
        float e = srm[PAD - d];  // uniform -> scalar load (scalar cache)
        int j = PAD - d;
        o0 = __builtin_fmaf(e, wf[j], o0);
        o1 = __builtin_fmaf(e, wf[j + 1], o1);
        o2 = __builtin_fmaf(e, wf[j + 2], o2);
        o3 = __builtin_fmaf(e, wf[j + 3], o3);
      }
      *(float4*)&pot1[(size_t)o * T_LEN + t0 + tloc] = make_float4(o0, o1, o2, o3);
    }
  }
}

// K4: pot2 = FIR129( z ),  z[t] = sum_o w2[o] * s1[o][t]  (bit-packed s1).
__global__ __launch_bounds__(TS) void k_pot2(const unsigned* __restrict__ s1p,
                                             const float* __restrict__ srm,
                                             const float* __restrict__ w2,
                                             float* __restrict__ pot2) {
  __shared__ float zs[TS + PAD];
  const int tid = threadIdx.x;
  const int t0 = blockIdx.x * TS;
  const int g0 = t0 - PAD;
  {
    int g = g0 + tid;
    float z = 0.0f;
    if (g >= 0) {
      int wi = g >> 5, sh = g & 31;
#pragma unroll
      for (int o = 0; o < NO1; ++o) {
        unsigned wv = s1p[o * NWORDS + wi];
        z += ((wv >> sh) & 1u) ? w2[o] : 0.0f;  // w2[o]: uniform scalar load
      }
    }
    zs[tid] = z;
    if (tid < PAD) {
      int g2 = g0 + TS + tid;  // always in [128, T_LEN)
      int wi = g2 >> 5, sh = g2 & 31;
      float z2 = 0.0f;
#pragma unroll
      for (int o = 0; o < NO1; ++o) {
        unsigned wv = s1p[o * NWORDS + wi];
        z2 += ((wv >> sh) & 1u) ? w2[o] : 0.0f;
      }
      zs[TS + tid] = z2;
    }
  }
  __syncthreads();
  float a = 0.0f;
#pragma unroll
  for (int d = 0; d < KTAPS; ++d) {
    float e = srm[PAD - d];
    a = __builtin_fmaf(e, zs[PAD + tid - d], a);
  }
  pot2[t0 + tid] = a;
}

// Speculative scan: one thread per (channel, block). WARM steps from assumed
// zero state, then LBLK emitted steps; records entry mask + exit mask/state.
template <int C, bool PACKED>
__global__ __launch_bounds__(256) void k_scan_spec(const float* __restrict__ pot,
                                                   const float* __restrict__ refk,
                                                   float* __restrict__ s,
                                                   unsigned* __restrict__ sp_,
                                                   unsigned* __restrict__ specin_m,
                                                   unsigned* __restrict__ specout_m,
                                                   float* __restrict__ specout_b) {
  int idx = blockIdx.x * 256 + threadIdx.x;
  if (idx >= C * NBK) return;
  int c = idx / NBK;
  int bb = idx - c * NBK;
  int tsr = bb * LBLK - WARM;
  float rn[15];
#pragma unroll
  for (int j = 0; j < 15; ++j) rn[j] = refk[j + 1];
  float b[15];
#pragma unroll
  for (int j = 0; j < 15; ++j) b[j] = 0.0f;
  unsigned m = 0;
  const float* prow = pot + (size_t)c * T_LEN;
  float* srow = PACKED ? nullptr : (s + (size_t)c * T_LEN);
  unsigned* srowp = PACKED ? (sp_ + (size_t)c * NWORDS) : nullptr;
  for (int k = 0; k < WARM + LBLK; k += 4) {
    if (k == WARM) specin_m[idx] = m & 0x7FFFu;
    int t = tsr + k;
    if (t < 0) continue;
    float4 pv = *(const float4*)(prow + t);
    float s0, s1v, s2, s3;
    srm_step(pv.x, rn, b, m, s0);
    srm_step(pv.y, rn, b, m, s1v);
    srm_step(pv.z, rn, b, m, s2);
    srm_step(pv.w, rn, b, m, s3);
    if (k >= WARM) {
      if (PACKED) {
        if (((t + 3) & 31) == 31) srowp[(t - 28) >> 5] = __brev(m);
      } else {
        *(float4*)(srow + t) = make_float4(s0, s1v, s2, s3);
      }
    }
  }
  specout_m[idx] = m & 0x7FFFu;
#pragma unroll
  for (int j = 0; j < 15; ++j) specout_b[idx * 16 + j] = b[j];
}

// Exact fixup: one WAVE per channel. Coalesced mask loads, ballot chain check
// (64 blocks/iter fast path); mismatches walked via shuffles + redundant
// per-lane recompute (same invariants as the scalar walk).
template <int C, bool PACKED>
__global__ __launch_bounds__(64) void k_scan_fix(const float* __restrict__ pot,
                                                 const float* __restrict__ refk,
                                                 float* __restrict__ s,
                                                 unsigned* __restrict__ sp_,
                                                 const unsigned* __restrict__ specin_m,
                                                 const unsigned* __restrict__ specout_m,
                                                 const float* __restrict__ specout_b) {
  const int c = blockIdx.x;
  const int lane = threadIdx.x;
  float rn[15];
#pragma unroll
  for (int j = 0; j < 15; ++j) rn[j] = refk[j + 1];
  float b[15];
#pragma unroll
  for (int j = 0; j < 15; ++j) b[j] = 0.0f;
  unsigned m = 0;
  bool haveB = true;
  const float* prow = pot + (size_t)c * T_LEN;
  float* srow = PACKED ? nullptr : (s + (size_t)c * T_LEN);
  unsigned* srowp = PACKED ? (sp_ + (size_t)c * NWORDS) : nullptr;
  unsigned prev_last = 0;  // spec exit mask of previous group's last block

  for (int g = 0; g < NBK / 64; ++g) {
    const int bb = g * 64 + lane;
    const unsigned si = specin_m[c * NBK + bb];
    const unsigned so = specout_m[c * NBK + bb];
    unsigned so_prev = __shfl_up(so, 1);
    if (lane == 0) so_prev = prev_last;
    const unsigned long long flags = __ballot(si == so_prev);
    prev_last = __shfl(so, 63);
    const unsigned si0 = __shfl(si, 0);
    if (flags == ~0ull && (m & 0x7FFFu) == si0) {
      m = prev_last;   // whole group chain-consistent => spec is truth
      haveB = false;
      continue;
    }
    // slow path: per-block walk from registers via shuffles
    for (int r = 0; r < 64; ++r) {
      const unsigned siv = __shfl(si, r);
      const unsigned sov = __shfl(so, r);
      if ((m & 0x7FFFu) == siv) {
        m = sov;
        haveB = false;
      } else {
        const int bbr = g * 64 + r;  // bbr>=1: block 0 entry mask 0 always matches
        if (!haveB) {
          const int pb = (c * NBK + bbr - 1) * 16;
#pragma unroll
          for (int q2 = 0; q2 < 15; ++q2) b[q2] = specout_b[pb + q2];
          haveB = true;
        }
        const int t0 = bbr * LBLK;
        for (int t = t0; t < t0 + LBLK; t += 4) {
          float4 pv = *(const float4*)(prow + t);  // uniform -> broadcast
          float s0, s1v, s2, s3;
          srm_step(pv.x, rn, b, m, s0);
          srm_step(pv.y, rn, b, m, s1v);
          srm_step(pv.z, rn, b, m, s2);
          srm_step(pv.w, rn, b, m, s3);
          if (PACKED) {
            if ((((t + 3) & 31) == 31) && lane == 0) srowp[(t - 28) >> 5] = __brev(m);
          } else {
            if (lane == 0) *(float4*)(srow + t) = make_float4(s0, s1v, s2, s3);
          }
        }
        haveB = true;
      }
    }
  }
}

extern "C" void kernel_launch(void* const* d_in, const int* in_sizes, int n_in,
                              void* d_out, int out_size, void* d_ws, size_t ws_size,
                              hipStream_t stream) {
  const float* x    = (const float*)d_in[0];  // 250*65536
  const float* srm  = (const float*)d_in[1];  // 257
  const float* refk = (const float*)d_in[2];  // 16
  const float* w1   = (const float*)d_in[3];  // 25*250
  const float* w2   = (const float*)d_in[4];  // 25
  float* out = (float*)d_out;

  float bad = 0.0f;
  if (n_in != 5) bad = 3.0f;
  else if (in_sizes[0] != NCH * T_LEN) bad = 4.0f;
  else if (in_sizes[1] != SRM_LEN)     bad = 5.0f;
  else if (in_sizes[2] != REF_LEN)     bad = 6.0f;
  else if (in_sizes[3] != NO1 * NCH)   bad = 7.0f;
  else if (in_sizes[4] != NO1)         bad = 8.0f;
  else if (out_size != T_LEN)          bad = 9.0f;
  if (bad != 0.0f) {
    k_fill<<<T_LEN / 256, 256, 0, stream>>>(out, bad);
    return;
  }

  size_t off = 0;
  auto alloc = [&](size_t bytes) { size_t o = off; off = (off + bytes + 255) & ~(size_t)255; return o; };
  char* ws = (char*)d_ws;
  size_t oP1  = alloc((size_t)NO1 * T_LEN * 4);        // 6.55 MB
  size_t oS1P = alloc((size_t)NO1 * NWORDS * 4);       // 205 KB
  size_t oP2  = alloc((size_t)T_LEN * 4);              // 262 KB
  size_t oSI1 = alloc((size_t)NO1 * NBK * 4);
  size_t oSO1 = alloc((size_t)NO1 * NBK * 4);
  size_t oSB1 = alloc((size_t)NO1 * NBK * 16 * 4);     // 819 KB
  size_t oSI2 = alloc((size_t)NBK * 4);
  size_t oSO2 = alloc((size_t)NBK * 4);
  size_t oSB2 = alloc((size_t)NBK * 16 * 4);
  if (ws_size < off) {
    k_fill<<<T_LEN / 256, 256, 0, stream>>>(out, 2.0f);
    return;
  }

  float*    pot1 = (float*)(ws + oP1);
  unsigned* s1p  = (unsigned*)(ws + oS1P);
  float*    pot2 = (float*)(ws + oP2);
  unsigned* si1  = (unsigned*)(ws + oSI1);
  unsigned* so1  = (unsigned*)(ws + oSO1);
  float*    sb1  = (float*)(ws + oSB1);
  unsigned* si2  = (unsigned*)(ws + oSI2);
  unsigned* so2  = (unsigned*)(ws + oSO2);
  float*    sb2  = (float*)(ws + oSB2);

  k_pot1<<<T_LEN / TS, TS, 0, stream>>>(x, w1, srm, pot1);
  k_scan_spec<NO1, true><<<(NO1 * NBK + 255) / 256, 256, 0, stream>>>(
      pot1, refk, nullptr, s1p, si1, so1, sb1);
  k_scan_fix<NO1, true><<<NO1, 64, 0, stream>>>(pot1, refk, nullptr, s1p, si1, so1, sb1);
  k_pot2<<<T_LEN / TS, TS, 0, stream>>>(s1p, srm, w2, pot2);
  k_scan_spec<1, false><<<(NBK + 255) / 256, 256, 0, stream>>>(
      pot2, refk, out, nullptr, si2, so2, sb2);
  k_scan_fix<1, false><<<1, 64, 0, stream>>>(pot2, refk, out, nullptr, si2, so2, sb2);
}